// Round 6
// baseline (369.044 us; speedup 1.0000x reference)
//
#include <hip/hip_runtime.h>
#include <hip/hip_fp16.h>

// Problem constants (fixed by reference)
constexpr int V_    = 2562;
constexpr int FIN_  = 8;
constexpr int FOUT_ = 16;
constexpr int S_    = 512;              // X*Y*Z
constexpr int VS_   = V_ * S_;          // elements per plane of in/out
constexpr int VP_   = 2564;             // V padded to %4==0 (16B-aligned rows)
constexpr long INT_PLANE = (long)S_ * VP_;   // elems per f-plane of inT / o-plane of y
constexpr int TPB   = 1024;
constexpr int NV    = 3;                // vertices per thread (ceil(2562/1024))

__device__ __forceinline__ float4 ld4(const float* p) {
    return *reinterpret_cast<const float4*>(p);
}
__device__ __forceinline__ void st4(float* p, float4 v) {
    *reinterpret_cast<float4*>(p) = v;
}
__device__ __forceinline__ unsigned h2bits(__half2 h) {
    union { __half2 h; unsigned u; } c; c.h = h; return c.u;
}
__device__ __forceinline__ __half2 bits2h(unsigned u) {
    union { unsigned u; __half2 h; } c; c.u = u; return c.h;
}
__device__ __forceinline__ unsigned packh2(float e, float o) {
    return h2bits(__halves2half2(__float2half(e), __float2half(o)));
}
__device__ __forceinline__ ushort f2h_bits(float x) {
    __half h = __float2half(x);
    return *reinterpret_cast<ushort*>(&h);
}

// ---------------------------------------------------------------------------
// transpose_g: dst[n][m] = src[m][n]  (fp32, per-z plane)
// src rows of srcStride elems (M rows, N valid cols); dst rows of dstStride.
// ---------------------------------------------------------------------------
__global__ __launch_bounds__(256)
void transpose_g(const float* __restrict__ src, float* __restrict__ dst,
                 int M, int N, int srcStride, int dstStride,
                 long srcZ, long dstZ)
{
    __shared__ float tile[64][65];
    const long zs = (long)blockIdx.z * srcZ;
    const long zd = (long)blockIdx.z * dstZ;
    const int n0 = blockIdx.x * 64;
    const int m0 = blockIdx.y * 64;
    const int t  = threadIdx.x;
    const int q  = t & 15;
    const int r  = t >> 4;

#pragma unroll
    for (int i = 0; i < 4; ++i) {
        const int m = m0 + r + i * 16;
        const int n = n0 + q * 4;
        if (m < M && n < N) {
            const float4 x = ld4(src + zs + (long)m * srcStride + n);
            tile[r + i * 16][q * 4 + 0] = x.x;
            tile[r + i * 16][q * 4 + 1] = x.y;
            tile[r + i * 16][q * 4 + 2] = x.z;
            tile[r + i * 16][q * 4 + 3] = x.w;
        }
    }
    __syncthreads();
#pragma unroll
    for (int i = 0; i < 4; ++i) {
        const int n = n0 + r + i * 16;
        const int m = m0 + q * 4;
        if (n < N && (m + 4) <= dstStride) {
            const float4 x = make_float4(tile[q * 4 + 0][r + i * 16],
                                         tile[q * 4 + 1][r + i * 16],
                                         tile[q * 4 + 2][r + i * 16],
                                         tile[q * 4 + 3][r + i * 16]);
            st4(dst + zd + (long)n * dstStride + m, x);
        }
    }
}

// ---------------------------------------------------------------------------
// transpose_h: dst[n][m] = f32(src[m][n])  (f16 src -> f32 dst, per-z plane)
// ---------------------------------------------------------------------------
__global__ __launch_bounds__(256)
void transpose_h(const ushort* __restrict__ src, float* __restrict__ dst,
                 int M, int N, int srcStride, int dstStride,
                 long srcZ, long dstZ)
{
    __shared__ float tile[64][65];
    const long zs = (long)blockIdx.z * srcZ;
    const long zd = (long)blockIdx.z * dstZ;
    const int n0 = blockIdx.x * 64;
    const int m0 = blockIdx.y * 64;
    const int t  = threadIdx.x;
    const int q  = t & 15;
    const int r  = t >> 4;

#pragma unroll
    for (int i = 0; i < 4; ++i) {
        const int m = m0 + r + i * 16;
        const int n = n0 + q * 4;
        if (m < M && n < N) {
            const uint2 u = *reinterpret_cast<const uint2*>(
                src + zs + (long)m * srcStride + n);      // 4 f16, 8B-aligned
            const __half2 h0 = bits2h(u.x);
            const __half2 h1 = bits2h(u.y);
            tile[r + i * 16][q * 4 + 0] = __half2float(__low2half(h0));
            tile[r + i * 16][q * 4 + 1] = __half2float(__high2half(h0));
            tile[r + i * 16][q * 4 + 2] = __half2float(__low2half(h1));
            tile[r + i * 16][q * 4 + 3] = __half2float(__high2half(h1));
        }
    }
    __syncthreads();
#pragma unroll
    for (int i = 0; i < 4; ++i) {
        const int n = n0 + r + i * 16;
        const int m = m0 + q * 4;
        if (n < N && (m + 4) <= dstStride) {
            const float4 x = make_float4(tile[q * 4 + 0][r + i * 16],
                                         tile[q * 4 + 1][r + i * 16],
                                         tile[q * 4 + 2][r + i * 16],
                                         tile[q * 4 + 3][r + i * 16]);
            st4(dst + zd + (long)n * dstStride + m, x);
        }
    }
}

// ---------------------------------------------------------------------------
// cheb_proj: FUSED recursion + projection, one s-slice per block.
// LDS state: cur4[v] = 8 f16 features (16B row). Per thread NV=3 vertices,
// acc[NV][16] fp32 accumulated over k=0..4 (bias folded in). cheb
// intermediate eliminated. Emits y[o][s][v] f16 (coalesced, v-fast).
// ---------------------------------------------------------------------------
__global__ __launch_bounds__(TPB)
void cheb_proj(const float* __restrict__ inT,   // [FIN][S][VP] f32
               const int*   __restrict__ cols,  // [V][8]
               const float* __restrict__ vals,  // [V][8]
               const float* __restrict__ W,     // [5][8][16]
               const float* __restrict__ bias,  // [16]
               ushort* __restrict__ y)          // [FOUT][S][VP] f16 bits
{
    __shared__ uint4 cur4[VP_];                 // 41024 B
    unsigned* curd = reinterpret_cast<unsigned*>(cur4);
    const int s = blockIdx.x;
    const int t = threadIdx.x;

    // fill: cur4[v] = {h2(f0,f1), h2(f2,f3), h2(f4,f5), h2(f6,f7)}
    {
        const int d  = t & 3;                   // feature-pair / dword index
        const float* p0 = inT + (long)(2 * d)     * INT_PLANE + (long)s * VP_;
        const float* p1 = inT + (long)(2 * d + 1) * INT_PLANE + (long)s * VP_;
        for (int c = t >> 2; c < VP_ / 4; c += TPB / 4) {
            const float4 xe = ld4(p0 + c * 4);
            const float4 xo = ld4(p1 + c * 4);
            curd[(c * 4 + 0) * 4 + d] = packh2(xe.x, xo.x);
            curd[(c * 4 + 1) * 4 + d] = packh2(xe.y, xo.y);
            curd[(c * 4 + 2) * 4 + d] = packh2(xe.z, xo.z);
            curd[(c * 4 + 3) * 4 + d] = packh2(xe.w, xo.w);
        }
    }
    __syncthreads();

    // xp = x0(own); acc = bias + W[k=0]·x0
    __half2 xp[NV][4];
    float acc[NV][16];
#pragma unroll
    for (int j = 0; j < NV; ++j) {
        const int v = (t + j * TPB < V_) ? (t + j * TPB) : 0;
        const uint4 r = cur4[v];
        xp[j][0] = bits2h(r.x); xp[j][1] = bits2h(r.y);
        xp[j][2] = bits2h(r.z); xp[j][3] = bits2h(r.w);
        float xf[8];
#pragma unroll
        for (int e = 0; e < 4; ++e) {
            xf[2 * e]     = __half2float(__low2half(xp[j][e]));
            xf[2 * e + 1] = __half2float(__high2half(xp[j][e]));
        }
#pragma unroll
        for (int o = 0; o < 16; ++o) {
            float a = bias[o];
#pragma unroll
            for (int f = 0; f < 8; ++f)
                a = fmaf(W[f * 16 + o], xf[f], a);
            acc[j][o] = a;
        }
    }

    const __half2 two2 = __half2half2(__float2half(2.0f));

#pragma unroll 1
    for (int k = 1; k < 5; ++k) {
        __half2 xk[NV][4];
#pragma unroll
        for (int j = 0; j < NV; ++j) {
            const bool valid = (t + j * TPB) < V_;
            const int v = valid ? (t + j * TPB) : 0;
            int off = v * 8;
            asm volatile("" : "+v"(off));       // block LICM of k-invariant loads
            const int4   ca = *reinterpret_cast<const int4*>(cols + off);
            const int4   cb = *reinterpret_cast<const int4*>(cols + off + 4);
            const float4 wa = ld4(vals + off);
            const float4 wb = ld4(vals + off + 4);
            const int   cc[8] = {ca.x, ca.y, ca.z, ca.w, cb.x, cb.y, cb.z, cb.w};
            const float ww[8] = {wa.x, wa.y, wa.z, wa.w, wb.x, wb.y, wb.z, wb.w};

            __half2 a4[4];
#pragma unroll
            for (int e = 0; e < 4; ++e) a4[e] = bits2h(0u);
#pragma unroll
            for (int n = 0; n < 8; ++n) {
                const uint4 rr = cur4[cc[n]];
                const __half2 w2 = __half2half2(__float2half(ww[n]));
                a4[0] = __hfma2(w2, bits2h(rr.x), a4[0]);
                a4[1] = __hfma2(w2, bits2h(rr.y), a4[1]);
                a4[2] = __hfma2(w2, bits2h(rr.z), a4[2]);
                a4[3] = __hfma2(w2, bits2h(rr.w), a4[3]);
            }
#pragma unroll
            for (int e = 0; e < 4; ++e)
                xk[j][e] = (k == 1) ? a4[e]
                                    : __hfma2(two2, a4[e], __hneg2(xp[j][e]));

            // projection-accumulate this k (f32 acc)
            float xf[8];
#pragma unroll
            for (int e = 0; e < 4; ++e) {
                xf[2 * e]     = __half2float(__low2half(xk[j][e]));
                xf[2 * e + 1] = __half2float(__high2half(xk[j][e]));
            }
#pragma unroll
            for (int f = 0; f < 8; ++f) {
#pragma unroll
                for (int o = 0; o < 16; ++o)
                    acc[j][o] = fmaf(W[(k * 8 + f) * 16 + o], xf[f], acc[j][o]);
            }

            // xp <- x_{k-1}(own) for next step (cur stable until barrier)
            if (k < 4) {
                const uint4 rr = cur4[v];
                xp[j][0] = bits2h(rr.x); xp[j][1] = bits2h(rr.y);
                xp[j][2] = bits2h(rr.z); xp[j][3] = bits2h(rr.w);
            }
        }
        if (k < 4) {
            __syncthreads();
#pragma unroll
            for (int j = 0; j < NV; ++j) {
                const int vr = t + j * TPB;
                if (vr < V_)
                    cur4[vr] = make_uint4(h2bits(xk[j][0]), h2bits(xk[j][1]),
                                          h2bits(xk[j][2]), h2bits(xk[j][3]));
            }
            __syncthreads();
        }
    }

    // emit y[o][s][v] f16 (lanes = consecutive v -> coalesced)
#pragma unroll
    for (int j = 0; j < NV; ++j) {
        const int v = t + j * TPB;
        if (v < V_) {
#pragma unroll
            for (int o = 0; o < 16; ++o)
                y[((long)o * S_ + s) * VP_ + v] = f2h_bits(acc[j][o]);
        }
    }
}

extern "C" void kernel_launch(void* const* d_in, const int* in_sizes, int n_in,
                              void* d_out, int out_size, void* d_ws, size_t ws_size,
                              hipStream_t stream) {
    const float* in   = (const float*)d_in[0];
    // d_in[1] = lap_rows == repeat(arange(V), DEG) by construction -> implicit
    const int*   cols = (const int*)d_in[2];
    const float* vals = (const float*)d_in[3];
    const float* W    = (const float*)d_in[4];
    const float* bias = (const float*)d_in[5];
    float* out = (float*)d_out;

    // inT (42 MB) borrows d_out (only read by cheb_proj, which completes
    // before transpose_h overwrites d_out). y f16 (42 MB) in d_ws.
    float*  inT = out;
    ushort* y   = (ushort*)d_ws;

    // T1: in[f][v][s] -> inT[f][s][v]
    transpose_g<<<dim3(8, 41, 8), 256, 0, stream>>>(
        in, inT, V_, S_, S_, VP_, (long)VS_, INT_PLANE);

    // Fused recursion + projection: inT -> y[o][s][v] (f16)
    cheb_proj<<<dim3(S_), TPB, 0, stream>>>(inT, cols, vals, W, bias, y);

    // T2: y[o][s][v] -> out[o][v][s] (f16 -> f32)
    transpose_h<<<dim3(41, 8, 16), 256, 0, stream>>>(
        y, out, S_, V_, VP_, S_, INT_PLANE, (long)VS_);
}

// Round 7
// 368.001 us; speedup vs baseline: 1.0028x; 1.0028x over previous
//
#include <hip/hip_runtime.h>
#include <hip/hip_fp16.h>

// Problem constants (fixed by reference)
constexpr int V_    = 2562;
constexpr int FIN_  = 8;
constexpr int FOUT_ = 16;
constexpr int S_    = 512;              // X*Y*Z
constexpr int VS_   = V_ * S_;          // elements per plane of in/out
constexpr int VP_   = 2564;             // V padded to %4==0 (16B-aligned rows)
constexpr long INT_PLANE = (long)S_ * VP_;   // elems per f-plane of inT / o-plane of y
constexpr int TPB   = 1024;
constexpr int NV    = 3;                // vertices per thread (ceil(2562/1024))

__device__ __forceinline__ float4 ld4(const float* p) {
    return *reinterpret_cast<const float4*>(p);
}
__device__ __forceinline__ void st4(float* p, float4 v) {
    *reinterpret_cast<float4*>(p) = v;
}
__device__ __forceinline__ unsigned h2bits(__half2 h) {
    union { __half2 h; unsigned u; } c; c.h = h; return c.u;
}
__device__ __forceinline__ __half2 bits2h(unsigned u) {
    union { unsigned u; __half2 h; } c; c.u = u; return c.h;
}
__device__ __forceinline__ unsigned packh2(float e, float o) {
    return h2bits(__halves2half2(__float2half(e), __float2half(o)));
}
__device__ __forceinline__ ushort f2h_bits(float x) {
    __half h = __float2half(x);
    return *reinterpret_cast<ushort*>(&h);
}

// ---------------------------------------------------------------------------
// transpose_g: dst[n][m] = src[m][n]  (fp32, per-z plane)
// ---------------------------------------------------------------------------
__global__ __launch_bounds__(256)
void transpose_g(const float* __restrict__ src, float* __restrict__ dst,
                 int M, int N, int srcStride, int dstStride,
                 long srcZ, long dstZ)
{
    __shared__ float tile[64][65];
    const long zs = (long)blockIdx.z * srcZ;
    const long zd = (long)blockIdx.z * dstZ;
    const int n0 = blockIdx.x * 64;
    const int m0 = blockIdx.y * 64;
    const int t  = threadIdx.x;
    const int q  = t & 15;
    const int r  = t >> 4;

#pragma unroll
    for (int i = 0; i < 4; ++i) {
        const int m = m0 + r + i * 16;
        const int n = n0 + q * 4;
        if (m < M && n < N) {
            const float4 x = ld4(src + zs + (long)m * srcStride + n);
            tile[r + i * 16][q * 4 + 0] = x.x;
            tile[r + i * 16][q * 4 + 1] = x.y;
            tile[r + i * 16][q * 4 + 2] = x.z;
            tile[r + i * 16][q * 4 + 3] = x.w;
        }
    }
    __syncthreads();
#pragma unroll
    for (int i = 0; i < 4; ++i) {
        const int n = n0 + r + i * 16;
        const int m = m0 + q * 4;
        if (n < N && (m + 4) <= dstStride) {
            const float4 x = make_float4(tile[q * 4 + 0][r + i * 16],
                                         tile[q * 4 + 1][r + i * 16],
                                         tile[q * 4 + 2][r + i * 16],
                                         tile[q * 4 + 3][r + i * 16]);
            st4(dst + zd + (long)n * dstStride + m, x);
        }
    }
}

// ---------------------------------------------------------------------------
// transpose_h: dst[n][m] = f32(src[m][n])  (f16 src -> f32 dst, per-z plane)
// ---------------------------------------------------------------------------
__global__ __launch_bounds__(256)
void transpose_h(const ushort* __restrict__ src, float* __restrict__ dst,
                 int M, int N, int srcStride, int dstStride,
                 long srcZ, long dstZ)
{
    __shared__ float tile[64][65];
    const long zs = (long)blockIdx.z * srcZ;
    const long zd = (long)blockIdx.z * dstZ;
    const int n0 = blockIdx.x * 64;
    const int m0 = blockIdx.y * 64;
    const int t  = threadIdx.x;
    const int q  = t & 15;
    const int r  = t >> 4;

#pragma unroll
    for (int i = 0; i < 4; ++i) {
        const int m = m0 + r + i * 16;
        const int n = n0 + q * 4;
        if (m < M && n < N) {
            const uint2 u = *reinterpret_cast<const uint2*>(
                src + zs + (long)m * srcStride + n);      // 4 f16, 8B-aligned
            const __half2 h0 = bits2h(u.x);
            const __half2 h1 = bits2h(u.y);
            tile[r + i * 16][q * 4 + 0] = __half2float(__low2half(h0));
            tile[r + i * 16][q * 4 + 1] = __half2float(__high2half(h0));
            tile[r + i * 16][q * 4 + 2] = __half2float(__low2half(h1));
            tile[r + i * 16][q * 4 + 3] = __half2float(__high2half(h1));
        }
    }
    __syncthreads();
#pragma unroll
    for (int i = 0; i < 4; ++i) {
        const int n = n0 + r + i * 16;
        const int m = m0 + q * 4;
        if (n < N && (m + 4) <= dstStride) {
            const float4 x = make_float4(tile[q * 4 + 0][r + i * 16],
                                         tile[q * 4 + 1][r + i * 16],
                                         tile[q * 4 + 2][r + i * 16],
                                         tile[q * 4 + 3][r + i * 16]);
            st4(dst + zd + (long)n * dstStride + m, x);
        }
    }
}

// ---------------------------------------------------------------------------
// cheb_proj: FUSED recursion + projection, one s-slice per block.
// __launch_bounds__(1024, 4): 4 waves/EU = 1 block/CU -> 128-VGPR budget.
// acc[3][16] fp32 + state ~100 VGPRs now fit WITHOUT scratch spill (R6's
// 64-VGPR default spilled ~900 MB of scratch traffic).
// ---------------------------------------------------------------------------
__global__ __launch_bounds__(TPB, 4)
void cheb_proj(const float* __restrict__ inT,   // [FIN][S][VP] f32
               const int*   __restrict__ cols,  // [V][8]
               const float* __restrict__ vals,  // [V][8]
               const float* __restrict__ W,     // [5][8][16]
               const float* __restrict__ bias,  // [16]
               ushort* __restrict__ y)          // [FOUT][S][VP] f16 bits
{
    __shared__ uint4 cur4[VP_];                 // 41024 B
    unsigned* curd = reinterpret_cast<unsigned*>(cur4);
    const int s = blockIdx.x;
    const int t = threadIdx.x;

    // fill: cur4[v] = {h2(f0,f1), h2(f2,f3), h2(f4,f5), h2(f6,f7)}
    {
        const int d  = t & 3;                   // feature-pair / dword index
        const float* p0 = inT + (long)(2 * d)     * INT_PLANE + (long)s * VP_;
        const float* p1 = inT + (long)(2 * d + 1) * INT_PLANE + (long)s * VP_;
        for (int c = t >> 2; c < VP_ / 4; c += TPB / 4) {
            const float4 xe = ld4(p0 + c * 4);
            const float4 xo = ld4(p1 + c * 4);
            curd[(c * 4 + 0) * 4 + d] = packh2(xe.x, xo.x);
            curd[(c * 4 + 1) * 4 + d] = packh2(xe.y, xo.y);
            curd[(c * 4 + 2) * 4 + d] = packh2(xe.z, xo.z);
            curd[(c * 4 + 3) * 4 + d] = packh2(xe.w, xo.w);
        }
    }
    __syncthreads();

    // xp = x0(own); acc = bias + W[k=0]·x0
    __half2 xp[NV][4];
    float acc[NV][16];
#pragma unroll
    for (int j = 0; j < NV; ++j) {
        const int v = (t + j * TPB < V_) ? (t + j * TPB) : 0;
        const uint4 r = cur4[v];
        xp[j][0] = bits2h(r.x); xp[j][1] = bits2h(r.y);
        xp[j][2] = bits2h(r.z); xp[j][3] = bits2h(r.w);
        float xf[8];
#pragma unroll
        for (int e = 0; e < 4; ++e) {
            xf[2 * e]     = __half2float(__low2half(xp[j][e]));
            xf[2 * e + 1] = __half2float(__high2half(xp[j][e]));
        }
#pragma unroll
        for (int o = 0; o < 16; ++o) {
            float a = bias[o];
#pragma unroll
            for (int f = 0; f < 8; ++f)
                a = fmaf(W[f * 16 + o], xf[f], a);
            acc[j][o] = a;
        }
    }

    const __half2 two2 = __half2half2(__float2half(2.0f));

#pragma unroll 1
    for (int k = 1; k < 5; ++k) {
        __half2 xk[NV][4];
#pragma unroll
        for (int j = 0; j < NV; ++j) {
            const bool valid = (t + j * TPB) < V_;
            const int v = valid ? (t + j * TPB) : 0;
            int off = v * 8;
            asm volatile("" : "+v"(off));       // block LICM of k-invariant loads
            const int4   ca = *reinterpret_cast<const int4*>(cols + off);
            const int4   cb = *reinterpret_cast<const int4*>(cols + off + 4);
            const float4 wa = ld4(vals + off);
            const float4 wb = ld4(vals + off + 4);
            const int   cc[8] = {ca.x, ca.y, ca.z, ca.w, cb.x, cb.y, cb.z, cb.w};
            const float ww[8] = {wa.x, wa.y, wa.z, wa.w, wb.x, wb.y, wb.z, wb.w};

            __half2 a4[4];
#pragma unroll
            for (int e = 0; e < 4; ++e) a4[e] = bits2h(0u);
#pragma unroll
            for (int n = 0; n < 8; ++n) {
                const uint4 rr = cur4[cc[n]];
                const __half2 w2 = __half2half2(__float2half(ww[n]));
                a4[0] = __hfma2(w2, bits2h(rr.x), a4[0]);
                a4[1] = __hfma2(w2, bits2h(rr.y), a4[1]);
                a4[2] = __hfma2(w2, bits2h(rr.z), a4[2]);
                a4[3] = __hfma2(w2, bits2h(rr.w), a4[3]);
            }
#pragma unroll
            for (int e = 0; e < 4; ++e)
                xk[j][e] = (k == 1) ? a4[e]
                                    : __hfma2(two2, a4[e], __hneg2(xp[j][e]));

            // projection-accumulate this k (f32 acc)
            float xf[8];
#pragma unroll
            for (int e = 0; e < 4; ++e) {
                xf[2 * e]     = __half2float(__low2half(xk[j][e]));
                xf[2 * e + 1] = __half2float(__high2half(xk[j][e]));
            }
#pragma unroll
            for (int f = 0; f < 8; ++f) {
#pragma unroll
                for (int o = 0; o < 16; ++o)
                    acc[j][o] = fmaf(W[(k * 8 + f) * 16 + o], xf[f], acc[j][o]);
            }

            // xp <- x_{k-1}(own) for next step (cur stable until barrier)
            if (k < 4) {
                const uint4 rr = cur4[v];
                xp[j][0] = bits2h(rr.x); xp[j][1] = bits2h(rr.y);
                xp[j][2] = bits2h(rr.z); xp[j][3] = bits2h(rr.w);
            }
        }
        if (k < 4) {
            __syncthreads();
#pragma unroll
            for (int j = 0; j < NV; ++j) {
                const int vr = t + j * TPB;
                if (vr < V_)
                    cur4[vr] = make_uint4(h2bits(xk[j][0]), h2bits(xk[j][1]),
                                          h2bits(xk[j][2]), h2bits(xk[j][3]));
            }
            __syncthreads();
        }
    }

    // emit y[o][s][v] f16 (lanes = consecutive v -> coalesced)
#pragma unroll
    for (int j = 0; j < NV; ++j) {
        const int v = t + j * TPB;
        if (v < V_) {
#pragma unroll
            for (int o = 0; o < 16; ++o)
                y[((long)o * S_ + s) * VP_ + v] = f2h_bits(acc[j][o]);
        }
    }
}

extern "C" void kernel_launch(void* const* d_in, const int* in_sizes, int n_in,
                              void* d_out, int out_size, void* d_ws, size_t ws_size,
                              hipStream_t stream) {
    const float* in   = (const float*)d_in[0];
    // d_in[1] = lap_rows == repeat(arange(V), DEG) by construction -> implicit
    const int*   cols = (const int*)d_in[2];
    const float* vals = (const float*)d_in[3];
    const float* W    = (const float*)d_in[4];
    const float* bias = (const float*)d_in[5];
    float* out = (float*)d_out;

    // inT (42 MB) borrows d_out (only read by cheb_proj, which completes
    // before transpose_h overwrites d_out). y f16 (42 MB) in d_ws.
    float*  inT = out;
    ushort* y   = (ushort*)d_ws;

    // T1: in[f][v][s] -> inT[f][s][v]
    transpose_g<<<dim3(8, 41, 8), 256, 0, stream>>>(
        in, inT, V_, S_, S_, VP_, (long)VS_, INT_PLANE);

    // Fused recursion + projection: inT -> y[o][s][v] (f16)
    cheb_proj<<<dim3(S_), TPB, 0, stream>>>(inT, cols, vals, W, bias, y);

    // T2: y[o][s][v] -> out[o][v][s] (f16 -> f32)
    transpose_h<<<dim3(41, 8, 16), 256, 0, stream>>>(
        y, out, S_, V_, VP_, S_, INT_PLANE, (long)VS_);
}

// Round 8
// 365.881 us; speedup vs baseline: 1.0086x; 1.0058x over previous
//
#include <hip/hip_runtime.h>
#include <hip/hip_fp16.h>

// Problem constants (fixed by reference)
constexpr int V_    = 2562;
constexpr int FIN_  = 8;
constexpr int FOUT_ = 16;
constexpr int S_    = 512;              // X*Y*Z
constexpr int VS_   = V_ * S_;          // elements per plane of in/out
constexpr int VP_   = 2564;             // V padded to %4==0 (16B-aligned rows)
constexpr long INT_PLANE = (long)S_ * VP_;   // elems per f-plane of inT / o-plane of y
constexpr int TPB   = 1024;
constexpr int NV    = 3;                // vertices per thread (ceil(2562/1024))

__device__ __forceinline__ float4 ld4(const float* p) {
    return *reinterpret_cast<const float4*>(p);
}
__device__ __forceinline__ void st4(float* p, float4 v) {
    *reinterpret_cast<float4*>(p) = v;
}
__device__ __forceinline__ unsigned h2bits(__half2 h) {
    union { __half2 h; unsigned u; } c; c.h = h; return c.u;
}
__device__ __forceinline__ __half2 bits2h(unsigned u) {
    union { unsigned u; __half2 h; } c; c.u = u; return c.h;
}
__device__ __forceinline__ unsigned packh2(float e, float o) {
    return h2bits(__halves2half2(__float2half(e), __float2half(o)));
}
__device__ __forceinline__ ushort f2h_bits(float x) {
    __half h = __float2half(x);
    return *reinterpret_cast<ushort*>(&h);
}

// ---------------------------------------------------------------------------
// transpose_g: dst[n][m] = src[m][n]  (fp32, per-z plane)
// ---------------------------------------------------------------------------
__global__ __launch_bounds__(256)
void transpose_g(const float* __restrict__ src, float* __restrict__ dst,
                 int M, int N, int srcStride, int dstStride,
                 long srcZ, long dstZ)
{
    __shared__ float tile[64][65];
    const long zs = (long)blockIdx.z * srcZ;
    const long zd = (long)blockIdx.z * dstZ;
    const int n0 = blockIdx.x * 64;
    const int m0 = blockIdx.y * 64;
    const int t  = threadIdx.x;
    const int q  = t & 15;
    const int r  = t >> 4;

#pragma unroll
    for (int i = 0; i < 4; ++i) {
        const int m = m0 + r + i * 16;
        const int n = n0 + q * 4;
        if (m < M && n < N) {
            const float4 x = ld4(src + zs + (long)m * srcStride + n);
            tile[r + i * 16][q * 4 + 0] = x.x;
            tile[r + i * 16][q * 4 + 1] = x.y;
            tile[r + i * 16][q * 4 + 2] = x.z;
            tile[r + i * 16][q * 4 + 3] = x.w;
        }
    }
    __syncthreads();
#pragma unroll
    for (int i = 0; i < 4; ++i) {
        const int n = n0 + r + i * 16;
        const int m = m0 + q * 4;
        if (n < N && (m + 4) <= dstStride) {
            const float4 x = make_float4(tile[q * 4 + 0][r + i * 16],
                                         tile[q * 4 + 1][r + i * 16],
                                         tile[q * 4 + 2][r + i * 16],
                                         tile[q * 4 + 3][r + i * 16]);
            st4(dst + zd + (long)n * dstStride + m, x);
        }
    }
}

// ---------------------------------------------------------------------------
// transpose_h: dst[n][m] = f32(src[m][n])  (f16 src -> f32 dst, per-z plane)
// ---------------------------------------------------------------------------
__global__ __launch_bounds__(256)
void transpose_h(const ushort* __restrict__ src, float* __restrict__ dst,
                 int M, int N, int srcStride, int dstStride,
                 long srcZ, long dstZ)
{
    __shared__ float tile[64][65];
    const long zs = (long)blockIdx.z * srcZ;
    const long zd = (long)blockIdx.z * dstZ;
    const int n0 = blockIdx.x * 64;
    const int m0 = blockIdx.y * 64;
    const int t  = threadIdx.x;
    const int q  = t & 15;
    const int r  = t >> 4;

#pragma unroll
    for (int i = 0; i < 4; ++i) {
        const int m = m0 + r + i * 16;
        const int n = n0 + q * 4;
        if (m < M && n < N) {
            const uint2 u = *reinterpret_cast<const uint2*>(
                src + zs + (long)m * srcStride + n);      // 4 f16, 8B-aligned
            const __half2 h0 = bits2h(u.x);
            const __half2 h1 = bits2h(u.y);
            tile[r + i * 16][q * 4 + 0] = __half2float(__low2half(h0));
            tile[r + i * 16][q * 4 + 1] = __half2float(__high2half(h0));
            tile[r + i * 16][q * 4 + 2] = __half2float(__low2half(h1));
            tile[r + i * 16][q * 4 + 3] = __half2float(__high2half(h1));
        }
    }
    __syncthreads();
#pragma unroll
    for (int i = 0; i < 4; ++i) {
        const int n = n0 + r + i * 16;
        const int m = m0 + q * 4;
        if (n < N && (m + 4) <= dstStride) {
            const float4 x = make_float4(tile[q * 4 + 0][r + i * 16],
                                         tile[q * 4 + 1][r + i * 16],
                                         tile[q * 4 + 2][r + i * 16],
                                         tile[q * 4 + 3][r + i * 16]);
            st4(dst + zd + (long)n * dstStride + m, x);
        }
    }
}

// ---------------------------------------------------------------------------
// cheb_proj: FUSED recursion + projection, one s-slice per block.
// amdgpu_waves_per_eu(4,4): pin EXACTLY 4 waves/EU (1 block/CU) ->
// 512/4 = 128-VGPR budget. R6/R7's 64-VGPR default spilled acc[3][16]
// to scratch (~900 MB of HBM round-trips). __launch_bounds__(1024,4)
// was ignored by the backend; the LLVM-native attribute is authoritative.
// ---------------------------------------------------------------------------
__global__
__attribute__((amdgpu_flat_work_group_size(TPB, TPB)))
__attribute__((amdgpu_waves_per_eu(4, 4)))
void cheb_proj(const float* __restrict__ inT,   // [FIN][S][VP] f32
               const int*   __restrict__ cols,  // [V][8]
               const float* __restrict__ vals,  // [V][8]
               const float* __restrict__ W,     // [5][8][16]
               const float* __restrict__ bias,  // [16]
               ushort* __restrict__ y)          // [FOUT][S][VP] f16 bits
{
    __shared__ uint4 cur4[VP_];                 // 41024 B
    unsigned* curd = reinterpret_cast<unsigned*>(cur4);
    const int s = blockIdx.x;
    const int t = threadIdx.x;

    // fill: cur4[v] = {h2(f0,f1), h2(f2,f3), h2(f4,f5), h2(f6,f7)}
    {
        const int d  = t & 3;                   // feature-pair / dword index
        const float* p0 = inT + (long)(2 * d)     * INT_PLANE + (long)s * VP_;
        const float* p1 = inT + (long)(2 * d + 1) * INT_PLANE + (long)s * VP_;
        for (int c = t >> 2; c < VP_ / 4; c += TPB / 4) {
            const float4 xe = ld4(p0 + c * 4);
            const float4 xo = ld4(p1 + c * 4);
            curd[(c * 4 + 0) * 4 + d] = packh2(xe.x, xo.x);
            curd[(c * 4 + 1) * 4 + d] = packh2(xe.y, xo.y);
            curd[(c * 4 + 2) * 4 + d] = packh2(xe.z, xo.z);
            curd[(c * 4 + 3) * 4 + d] = packh2(xe.w, xo.w);
        }
    }
    __syncthreads();

    // xp = x0(own); acc = bias + W[k=0]·x0
    __half2 xp[NV][4];
    float acc[NV][16];
#pragma unroll
    for (int j = 0; j < NV; ++j) {
        const int v = (t + j * TPB < V_) ? (t + j * TPB) : 0;
        const uint4 r = cur4[v];
        xp[j][0] = bits2h(r.x); xp[j][1] = bits2h(r.y);
        xp[j][2] = bits2h(r.z); xp[j][3] = bits2h(r.w);
        float xf[8];
#pragma unroll
        for (int e = 0; e < 4; ++e) {
            xf[2 * e]     = __half2float(__low2half(xp[j][e]));
            xf[2 * e + 1] = __half2float(__high2half(xp[j][e]));
        }
#pragma unroll
        for (int o = 0; o < 16; ++o) {
            float a = bias[o];
#pragma unroll
            for (int f = 0; f < 8; ++f)
                a = fmaf(W[f * 16 + o], xf[f], a);
            acc[j][o] = a;
        }
    }

    const __half2 two2 = __half2half2(__float2half(2.0f));

#pragma unroll 1
    for (int k = 1; k < 5; ++k) {
        __half2 xk[NV][4];
#pragma unroll
        for (int j = 0; j < NV; ++j) {
            const bool valid = (t + j * TPB) < V_;
            const int v = valid ? (t + j * TPB) : 0;
            int off = v * 8;
            asm volatile("" : "+v"(off));       // block LICM of k-invariant loads
            const int4   ca = *reinterpret_cast<const int4*>(cols + off);
            const int4   cb = *reinterpret_cast<const int4*>(cols + off + 4);
            const float4 wa = ld4(vals + off);
            const float4 wb = ld4(vals + off + 4);
            const int   cc[8] = {ca.x, ca.y, ca.z, ca.w, cb.x, cb.y, cb.z, cb.w};
            const float ww[8] = {wa.x, wa.y, wa.z, wa.w, wb.x, wb.y, wb.z, wb.w};

            __half2 a4[4];
#pragma unroll
            for (int e = 0; e < 4; ++e) a4[e] = bits2h(0u);
#pragma unroll
            for (int n = 0; n < 8; ++n) {
                const uint4 rr = cur4[cc[n]];
                const __half2 w2 = __half2half2(__float2half(ww[n]));
                a4[0] = __hfma2(w2, bits2h(rr.x), a4[0]);
                a4[1] = __hfma2(w2, bits2h(rr.y), a4[1]);
                a4[2] = __hfma2(w2, bits2h(rr.z), a4[2]);
                a4[3] = __hfma2(w2, bits2h(rr.w), a4[3]);
            }
#pragma unroll
            for (int e = 0; e < 4; ++e)
                xk[j][e] = (k == 1) ? a4[e]
                                    : __hfma2(two2, a4[e], __hneg2(xp[j][e]));

            // projection-accumulate this k (f32 acc)
            float xf[8];
#pragma unroll
            for (int e = 0; e < 4; ++e) {
                xf[2 * e]     = __half2float(__low2half(xk[j][e]));
                xf[2 * e + 1] = __half2float(__high2half(xk[j][e]));
            }
#pragma unroll
            for (int f = 0; f < 8; ++f) {
#pragma unroll
                for (int o = 0; o < 16; ++o)
                    acc[j][o] = fmaf(W[(k * 8 + f) * 16 + o], xf[f], acc[j][o]);
            }

            // xp <- x_{k-1}(own) for next step (cur stable until barrier)
            if (k < 4) {
                const uint4 rr = cur4[v];
                xp[j][0] = bits2h(rr.x); xp[j][1] = bits2h(rr.y);
                xp[j][2] = bits2h(rr.z); xp[j][3] = bits2h(rr.w);
            }
        }
        if (k < 4) {
            __syncthreads();
#pragma unroll
            for (int j = 0; j < NV; ++j) {
                const int vr = t + j * TPB;
                if (vr < V_)
                    cur4[vr] = make_uint4(h2bits(xk[j][0]), h2bits(xk[j][1]),
                                          h2bits(xk[j][2]), h2bits(xk[j][3]));
            }
            __syncthreads();
        }
    }

    // emit y[o][s][v] f16 (lanes = consecutive v -> coalesced)
#pragma unroll
    for (int j = 0; j < NV; ++j) {
        const int v = t + j * TPB;
        if (v < V_) {
#pragma unroll
            for (int o = 0; o < 16; ++o)
                y[((long)o * S_ + s) * VP_ + v] = f2h_bits(acc[j][o]);
        }
    }
}

extern "C" void kernel_launch(void* const* d_in, const int* in_sizes, int n_in,
                              void* d_out, int out_size, void* d_ws, size_t ws_size,
                              hipStream_t stream) {
    const float* in   = (const float*)d_in[0];
    // d_in[1] = lap_rows == repeat(arange(V), DEG) by construction -> implicit
    const int*   cols = (const int*)d_in[2];
    const float* vals = (const float*)d_in[3];
    const float* W    = (const float*)d_in[4];
    const float* bias = (const float*)d_in[5];
    float* out = (float*)d_out;

    // inT (42 MB) borrows d_out (only read by cheb_proj, which completes
    // before transpose_h overwrites d_out). y f16 (42 MB) in d_ws.
    float*  inT = out;
    ushort* y   = (ushort*)d_ws;

    // T1: in[f][v][s] -> inT[f][s][v]
    transpose_g<<<dim3(8, 41, 8), 256, 0, stream>>>(
        in, inT, V_, S_, S_, VP_, (long)VS_, INT_PLANE);

    // Fused recursion + projection: inT -> y[o][s][v] (f16)
    cheb_proj<<<dim3(S_), TPB, 0, stream>>>(inT, cols, vals, W, bias, y);

    // T2: y[o][s][v] -> out[o][v][s] (f16 -> f32)
    transpose_h<<<dim3(41, 8, 16), 256, 0, stream>>>(
        y, out, S_, V_, VP_, S_, INT_PLANE, (long)VS_);
}

// Round 9
// 187.877 us; speedup vs baseline: 1.9643x; 1.9475x over previous
//
#include <hip/hip_runtime.h>
#include <hip/hip_fp16.h>

// Problem constants (fixed by reference)
constexpr int V_    = 2562;
constexpr int FIN_  = 8;
constexpr int FOUT_ = 16;
constexpr int S_    = 512;              // X*Y*Z
constexpr int SP_   = 256;              // S/2 (s-pair rows)
constexpr int VS_   = V_ * S_;          // elements per plane of in/out
constexpr int VP_   = 2564;             // V padded to %4==0 (16B-aligned rows)
constexpr int LSTR  = 12;               // LDS dwords per vertex (8 used + 4 pad)
constexpr long PLH  = (long)SP_ * VP_;  // inTh plane stride (uints = half2)
constexpr long PS   = (long)S_ * V_ * 8; // cheb plane stride (ushorts)
constexpr int TPB   = 1024;
constexpr int NV    = 3;                // vertices per thread (ceil(2562/1024))

__device__ __forceinline__ float4 ld4(const float* p) {
    return *reinterpret_cast<const float4*>(p);
}
__device__ __forceinline__ void st4(float* p, float4 v) {
    *reinterpret_cast<float4*>(p) = v;
}
__device__ __forceinline__ unsigned h2bits(__half2 h) {
    union { __half2 h; unsigned u; } c; c.h = h; return c.u;
}
__device__ __forceinline__ __half2 bits2h(unsigned u) {
    union { unsigned u; __half2 h; } c; c.u = u; return c.h;
}
__device__ __forceinline__ unsigned packh2(float e, float o) {
    return h2bits(__halves2half2(__float2half(e), __float2half(o)));
}

// ---------------------------------------------------------------------------
// transpose_pack: in[f][v][s] f32 -> inTh[f][s/2][v] half2(s-even, s-odd).
// Same tile transpose as before but emits f16-packed pairs (63 MB total
// traffic vs 84). The f16 rounding here is the SAME rounding cheb_rec's
// LDS fill already applied — numerics unchanged.
// ---------------------------------------------------------------------------
__global__ __launch_bounds__(256)
void transpose_pack(const float* __restrict__ src, unsigned* __restrict__ dst)
{
    __shared__ float tile[64][65];
    const int f  = blockIdx.z;
    const int n0 = blockIdx.x * 64;          // s base
    const int m0 = blockIdx.y * 64;          // v base
    const int t  = threadIdx.x;
    const int q  = t & 15;
    const int r  = t >> 4;
    const float* sp_ = src + (long)f * VS_;

#pragma unroll
    for (int i = 0; i < 4; ++i) {
        const int m = m0 + r + i * 16;
        const int n = n0 + q * 4;
        if (m < V_) {
            const float4 x = ld4(sp_ + (long)m * S_ + n);
            tile[r + i * 16][q * 4 + 0] = x.x;
            tile[r + i * 16][q * 4 + 1] = x.y;
            tile[r + i * 16][q * 4 + 2] = x.z;
            tile[r + i * 16][q * 4 + 3] = x.w;
        }
    }
    __syncthreads();

    // write: 32 s-pair rows x 16 v-quads (uint4 = 4 v x half2)
#pragma unroll
    for (int i = 0; i < 2; ++i) {
        const int idx = t + i * 256;         // 0..511
        const int vq  = idx & 15;
        const int sp  = idx >> 4;            // 0..31
        const int m   = m0 + vq * 4;
        if (m + 4 <= VP_) {
            unsigned u[4];
#pragma unroll
            for (int e = 0; e < 4; ++e)
                u[e] = packh2(tile[vq * 4 + e][2 * sp],
                              tile[vq * 4 + e][2 * sp + 1]);
            *reinterpret_cast<uint4*>(
                dst + (long)f * PLH + (long)(n0 / 2 + sp) * VP_ + m) =
                make_uint4(u[0], u[1], u[2], u[3]);
        }
    }
}

// ---------------------------------------------------------------------------
// cheb_rec: TWO s-slices per block, state packed f16x2 in LDS (verified
// 64-VGPR R4 structure). Fill now reads the pre-packed inTh directly
// (one uint4 load, no conversion). Emits x1..x4 to chebX1 planes and,
// when x0p != null (5-plane mode), also emits the x0 plane.
// ---------------------------------------------------------------------------
__global__ __launch_bounds__(TPB)
void cheb_rec(const unsigned* __restrict__ inTh, // [8][SP][VP] half2
              const int*   __restrict__ cols,    // [V][8]
              const float* __restrict__ vals,    // [V][8]
              ushort* __restrict__ chebX1,       // planes x1..x4
              ushort* __restrict__ x0p)          // plane x0 (or null)
{
    extern __shared__ unsigned cur[];            // VP_*LSTR dwords = 123072 B
    const int s2 = blockIdx.x * 2;               // even slice; odd = s2+1
    const int t  = threadIdx.x;

    // fill cur[v*12 + f] = inTh[f][s2/2][v]  (already half2-packed)
    {
        const int f  = t & 7;
        const int cb = t >> 3;
        const unsigned* pl = inTh + (long)f * PLH + (long)blockIdx.x * VP_;
        for (int c = cb; c < VP_ / 4; c += TPB / 8) {
            const uint4 u = *reinterpret_cast<const uint4*>(pl + c * 4);
            cur[(c * 4 + 0) * LSTR + f] = u.x;
            cur[(c * 4 + 1) * LSTR + f] = u.y;
            cur[(c * 4 + 2) * LSTR + f] = u.z;
            cur[(c * 4 + 3) * LSTR + f] = u.w;
        }
    }
    __syncthreads();

    // 5-plane mode: emit x0 plane from the freshly filled LDS
    if (x0p) {
#pragma unroll
        for (int j = 0; j < NV; ++j) {
            const int v = t + j * TPB;
            if (v < V_) {
                const uint4 lo = *reinterpret_cast<const uint4*>(&cur[v * LSTR]);
                const uint4 hi = *reinterpret_cast<const uint4*>(&cur[v * LSTR + 4]);
                const unsigned p0[4] = { lo.x, lo.z, hi.x, hi.z };
                const unsigned p1[4] = { lo.y, lo.w, hi.y, hi.w };
                unsigned ue[4], uo[4];
#pragma unroll
                for (int i = 0; i < 4; ++i) {
                    ue[i] = __builtin_amdgcn_perm(p1[i], p0[i], 0x05040100u);
                    uo[i] = __builtin_amdgcn_perm(p1[i], p0[i], 0x07060302u);
                }
                const long base = ((long)s2 * V_ + v) * 8;
                *reinterpret_cast<uint4*>(x0p + base) =
                    make_uint4(ue[0], ue[1], ue[2], ue[3]);
                *reinterpret_cast<uint4*>(x0p + base + (long)V_ * 8) =
                    make_uint4(uo[0], uo[1], uo[2], uo[3]);
            }
        }
    }

    const __half2 two2 = __half2half2(__float2half(2.0f));

    __half2 xp[NV][8];      // x_{k-2} at own vertices (starts as x0)
#pragma unroll
    for (int j = 0; j < NV; ++j) {
        const int v = (t + j * TPB < V_) ? (t + j * TPB) : 0;
        const uint4 lo = *reinterpret_cast<const uint4*>(&cur[v * LSTR]);
        const uint4 hi = *reinterpret_cast<const uint4*>(&cur[v * LSTR + 4]);
        xp[j][0] = bits2h(lo.x); xp[j][1] = bits2h(lo.y);
        xp[j][2] = bits2h(lo.z); xp[j][3] = bits2h(lo.w);
        xp[j][4] = bits2h(hi.x); xp[j][5] = bits2h(hi.y);
        xp[j][6] = bits2h(hi.z); xp[j][7] = bits2h(hi.w);
    }

#pragma unroll 1
    for (int k = 1; k < 5; ++k) {
        __half2 xk[NV][8];
#pragma unroll
        for (int j = 0; j < NV; ++j) {
            const bool valid = (t + j * TPB) < V_;
            const int v = valid ? (t + j * TPB) : 0;
            int off = v * 8;
            asm volatile("" : "+v"(off));       // block LICM of k-invariant loads
            const int4   ca = *reinterpret_cast<const int4*>(cols + off);
            const int4   cb = *reinterpret_cast<const int4*>(cols + off + 4);
            const float4 wa = ld4(vals + off);
            const float4 wb = ld4(vals + off + 4);
            const int   cc[8] = {ca.x, ca.y, ca.z, ca.w, cb.x, cb.y, cb.z, cb.w};
            const float ww[8] = {wa.x, wa.y, wa.z, wa.w, wb.x, wb.y, wb.z, wb.w};

            __half2 a[8];
#pragma unroll
            for (int e = 0; e < 8; ++e) a[e] = bits2h(0u);
#pragma unroll
            for (int n = 0; n < 8; ++n) {
                const unsigned* p = &cur[cc[n] * LSTR];
                const uint4 lo = *reinterpret_cast<const uint4*>(p);
                const uint4 hi = *reinterpret_cast<const uint4*>(p + 4);
                const __half2 w2 = __half2half2(__float2half(ww[n]));
                a[0] = __hfma2(w2, bits2h(lo.x), a[0]);
                a[1] = __hfma2(w2, bits2h(lo.y), a[1]);
                a[2] = __hfma2(w2, bits2h(lo.z), a[2]);
                a[3] = __hfma2(w2, bits2h(lo.w), a[3]);
                a[4] = __hfma2(w2, bits2h(hi.x), a[4]);
                a[5] = __hfma2(w2, bits2h(hi.y), a[5]);
                a[6] = __hfma2(w2, bits2h(hi.z), a[6]);
                a[7] = __hfma2(w2, bits2h(hi.w), a[7]);
            }
#pragma unroll
            for (int e = 0; e < 8; ++e)
                xk[j][e] = (k == 1) ? a[e]
                                    : __hfma2(two2, a[e], __hneg2(xp[j][e]));

            // emit both slices: v_perm extracts lo/hi f16 halves into dwords
            if (valid) {
                unsigned ue[4], uo[4];
#pragma unroll
                for (int i = 0; i < 4; ++i) {
                    const unsigned b0 = h2bits(xk[j][2 * i]);
                    const unsigned b1 = h2bits(xk[j][2 * i + 1]);
                    ue[i] = __builtin_amdgcn_perm(b1, b0, 0x05040100u); // even s
                    uo[i] = __builtin_amdgcn_perm(b1, b0, 0x07060302u); // odd  s
                }
                const long base = (((long)(k - 1) * S_ + s2) * V_ + v) * 8;
                *reinterpret_cast<uint4*>(chebX1 + base) =
                    make_uint4(ue[0], ue[1], ue[2], ue[3]);
                *reinterpret_cast<uint4*>(chebX1 + base + (long)V_ * 8) =
                    make_uint4(uo[0], uo[1], uo[2], uo[3]);
            }

            // stage next xprev = x_{k-1}[own] (cur stable until barrier)
            if (k < 4) {
                const uint4 lo = *reinterpret_cast<const uint4*>(&cur[v * LSTR]);
                const uint4 hi = *reinterpret_cast<const uint4*>(&cur[v * LSTR + 4]);
                xp[j][0] = bits2h(lo.x); xp[j][1] = bits2h(lo.y);
                xp[j][2] = bits2h(lo.z); xp[j][3] = bits2h(lo.w);
                xp[j][4] = bits2h(hi.x); xp[j][5] = bits2h(hi.y);
                xp[j][6] = bits2h(hi.z); xp[j][7] = bits2h(hi.w);
            }
        }
        if (k < 4) {
            __syncthreads();
#pragma unroll
            for (int j = 0; j < NV; ++j) {
                const int vr = t + j * TPB;
                if (vr < V_) {
                    *reinterpret_cast<uint4*>(&cur[vr * LSTR]) =
                        make_uint4(h2bits(xk[j][0]), h2bits(xk[j][1]),
                                   h2bits(xk[j][2]), h2bits(xk[j][3]));
                    *reinterpret_cast<uint4*>(&cur[vr * LSTR + 4]) =
                        make_uint4(h2bits(xk[j][4]), h2bits(xk[j][5]),
                                   h2bits(xk[j][6]), h2bits(xk[j][7]));
                }
            }
            __syncthreads();
        }
    }
}

// ---------------------------------------------------------------------------
// proj5: out[o][v][s] = bias[o] + sum_{k,f} W[k,f,o] * x_k[f,v,s]
// 5-plane cheb (x0 included) -> NO `in` read, NO x0t staging phase,
// ONE barrier. 5 prefetched int4 + 640 FMAs + one-shot LDS transpose.
// ---------------------------------------------------------------------------
__global__ __launch_bounds__(TPB)
void proj5(const ushort* __restrict__ cheb,      // [5][S][V][8] f16 bits
           const float* __restrict__ W,          // [5][8][16]
           const float* __restrict__ bias,       // [16]
           float* __restrict__ out)              // [FOUT][V][S]
{
    extern __shared__ float sm[];                // 16*64*17 floats = 69632 B
    const int v0 = blockIdx.x * 64;
    const int s0 = blockIdx.y * 16;
    const int t  = threadIdx.x;
    const int tv = t & 63;
    const int ts = t >> 6;
    const int vg = (v0 + tv < V_) ? (v0 + tv) : (V_ - 1);

    int4 ck[5];
#pragma unroll
    for (int k = 0; k < 5; ++k)
        ck[k] = *reinterpret_cast<const int4*>(
            cheb + (long)k * PS + ((long)(s0 + ts) * V_ + vg) * 8);

    float acc[16];
#pragma unroll
    for (int o = 0; o < 16; ++o) acc[o] = bias[o];

#pragma unroll
    for (int k = 0; k < 5; ++k) {
        union { int4 q; __half u[8]; } pk;
        pk.q = ck[k];
        float xf[8];
#pragma unroll
        for (int f = 0; f < 8; ++f)
            xf[f] = __half2float(pk.u[f]);
#pragma unroll
        for (int f = 0; f < 8; ++f) {
#pragma unroll
            for (int o = 0; o < 16; ++o)
                acc[o] = fmaf(W[(k * 8 + f) * 16 + o], xf[f], acc[o]);
        }
    }

    // one-shot staging: all 16 o planes, then vectorized stores
#pragma unroll
    for (int o = 0; o < 16; ++o)
        sm[o * 1088 + tv * 17 + ts] = acc[o];
    __syncthreads();
#pragma unroll
    for (int p = 0; p < 4; ++p) {
        const int idx = t + p * TPB;             // 0..4095
        const int sq  = idx & 3;
        const int v   = (idx >> 2) & 63;
        const int o   = idx >> 8;                // 0..15
        if (v0 + v < V_) {
            const float* r = &sm[o * 1088 + v * 17 + sq * 4];
            st4(out + (long)o * VS_ + (long)(v0 + v) * S_ + s0 + sq * 4,
                make_float4(r[0], r[1], r[2], r[3]));
        }
    }
}

// ---------------------------------------------------------------------------
// proj4: fallback when ws_size < 5 planes — R5's verified proj (in + 4-plane
// cheb, x0t staging, prefetch, one-shot output staging).
// ---------------------------------------------------------------------------
__global__ __launch_bounds__(TPB)
void proj4(const float* __restrict__ in,         // [FIN][V][S]
           const ushort* __restrict__ cheb,      // [4][S][V][8] f16 bits
           const float* __restrict__ W,
           const float* __restrict__ bias,
           float* __restrict__ out)
{
    extern __shared__ float sm[];                // 16*64*17 floats
    const int v0 = blockIdx.x * 64;
    const int s0 = blockIdx.y * 16;
    const int t  = threadIdx.x;
    const int tv = t & 63;
    const int ts = t >> 6;
    const int vg = (v0 + tv < V_) ? (v0 + tv) : (V_ - 1);

    int4 ck[4];
#pragma unroll
    for (int k = 0; k < 4; ++k)
        ck[k] = *reinterpret_cast<const int4*>(
            cheb + (long)k * PS + ((long)(s0 + ts) * V_ + vg) * 8);

#pragma unroll
    for (int p = 0; p < 2; ++p) {
        const int idx = t + p * TPB;
        const int sq  = idx & 3;
        const int v   = (idx >> 2) & 63;
        const int f   = idx >> 8;
        const int vvg = (v0 + v < V_) ? (v0 + v) : (V_ - 1);
        const float4 x = ld4(in + (long)f * VS_ + (long)vvg * S_ + s0 + sq * 4);
        float* d = &sm[f * 1088 + v * 17 + sq * 4];
        d[0] = x.x; d[1] = x.y; d[2] = x.z; d[3] = x.w;
    }
    __syncthreads();

    float acc[16];
#pragma unroll
    for (int o = 0; o < 16; ++o) acc[o] = bias[o];

#pragma unroll
    for (int f = 0; f < FIN_; ++f) {
        const float xv = sm[f * 1088 + tv * 17 + ts];
#pragma unroll
        for (int o = 0; o < 16; ++o)
            acc[o] = fmaf(W[f * 16 + o], xv, acc[o]);
    }
#pragma unroll
    for (int k = 1; k < 5; ++k) {
        union { int4 q; __half u[8]; } pk;
        pk.q = ck[k - 1];
        float xf[8];
#pragma unroll
        for (int f = 0; f < 8; ++f)
            xf[f] = __half2float(pk.u[f]);
#pragma unroll
        for (int f = 0; f < 8; ++f) {
#pragma unroll
            for (int o = 0; o < 16; ++o)
                acc[o] = fmaf(W[(k * 8 + f) * 16 + o], xf[f], acc[o]);
        }
    }

    __syncthreads();
#pragma unroll
    for (int o = 0; o < 16; ++o)
        sm[o * 1088 + tv * 17 + ts] = acc[o];
    __syncthreads();
#pragma unroll
    for (int p = 0; p < 4; ++p) {
        const int idx = t + p * TPB;
        const int sq  = idx & 3;
        const int v   = (idx >> 2) & 63;
        const int o   = idx >> 8;
        if (v0 + v < V_) {
            const float* r = &sm[o * 1088 + v * 17 + sq * 4];
            st4(out + (long)o * VS_ + (long)(v0 + v) * S_ + s0 + sq * 4,
                make_float4(r[0], r[1], r[2], r[3]));
        }
    }
}

extern "C" void kernel_launch(void* const* d_in, const int* in_sizes, int n_in,
                              void* d_out, int out_size, void* d_ws, size_t ws_size,
                              hipStream_t stream) {
    const float* in   = (const float*)d_in[0];
    // d_in[1] = lap_rows == repeat(arange(V), DEG) by construction -> implicit
    const int*   cols = (const int*)d_in[2];
    const float* vals = (const float*)d_in[3];
    const float* W    = (const float*)d_in[4];
    const float* bias = (const float*)d_in[5];
    float* out = (float*)d_out;

    // inTh f16 (21 MB) borrows d_out (fully consumed by cheb_rec before
    // proj overwrites d_out). cheb planes live in d_ws:
    //   5-plane mode (x0..x4, 105 MB) if workspace allows, else 4-plane.
    unsigned* inTh = (unsigned*)d_out;
    const bool five = ws_size >= (size_t)(5 * PS * 2);
    ushort* wsu    = (ushort*)d_ws;
    ushort* x0p    = five ? wsu : nullptr;
    ushort* chebX1 = five ? wsu + PS : wsu;

    (void)hipFuncSetAttribute((const void*)cheb_rec,
                              hipFuncAttributeMaxDynamicSharedMemorySize,
                              VP_ * LSTR * (int)sizeof(unsigned));
    (void)hipFuncSetAttribute((const void*)proj5,
                              hipFuncAttributeMaxDynamicSharedMemorySize,
                              16 * 64 * 17 * (int)sizeof(float));
    (void)hipFuncSetAttribute((const void*)proj4,
                              hipFuncAttributeMaxDynamicSharedMemorySize,
                              16 * 64 * 17 * (int)sizeof(float));

    // T1: in[f][v][s] f32 -> inTh[f][s/2][v] half2
    transpose_pack<<<dim3(8, 41, 8), 256, 0, stream>>>(in, inTh);

    // Recursion: 2 s-slices per block, emit x1..x4 (+x0 in 5-plane mode)
    cheb_rec<<<dim3(SP_), TPB, VP_ * LSTR * (int)sizeof(unsigned), stream>>>(
        inTh, cols, vals, chebX1, x0p);

    // Projection + output transpose
    if (five)
        proj5<<<dim3(41, 32), TPB, 16 * 64 * 17 * (int)sizeof(float), stream>>>(
            wsu, W, bias, out);
    else
        proj4<<<dim3(41, 32), TPB, 16 * 64 * 17 * (int)sizeof(float), stream>>>(
            in, chebX1, W, bias, out);
}

// Round 10
// 186.392 us; speedup vs baseline: 1.9799x; 1.0080x over previous
//
#include <hip/hip_runtime.h>
#include <hip/hip_fp16.h>

// Problem constants (fixed by reference)
constexpr int V_    = 2562;
constexpr int FIN_  = 8;
constexpr int FOUT_ = 16;
constexpr int S_    = 512;              // X*Y*Z
constexpr int SP_   = 256;              // S/2 (s-pair rows)
constexpr int VS_   = V_ * S_;          // elements per plane of in/out
constexpr int VP_   = 2564;             // V padded to %4==0 (16B-aligned rows)
constexpr int LSTR  = 12;               // LDS dwords per vertex (8 used + 4 pad)
constexpr long PLH  = (long)SP_ * VP_;  // inTh plane stride (uints = half2)
constexpr long PS   = (long)S_ * V_ * 8; // cheb plane stride (ushorts)
constexpr int TPB   = 1024;
constexpr int NV    = 3;                // vertices per thread (ceil(2562/1024))

__device__ __forceinline__ float4 ld4(const float* p) {
    return *reinterpret_cast<const float4*>(p);
}
__device__ __forceinline__ void st4(float* p, float4 v) {
    *reinterpret_cast<float4*>(p) = v;
}
__device__ __forceinline__ unsigned h2bits(__half2 h) {
    union { __half2 h; unsigned u; } c; c.h = h; return c.u;
}
__device__ __forceinline__ __half2 bits2h(unsigned u) {
    union { unsigned u; __half2 h; } c; c.u = u; return c.h;
}
__device__ __forceinline__ unsigned packh2(float e, float o) {
    return h2bits(__halves2half2(__float2half(e), __float2half(o)));
}

// ---------------------------------------------------------------------------
// transpose_pack: in[f][v][s] f32 -> inTh[f][s/2][v] half2(s-even, s-odd).
// ---------------------------------------------------------------------------
__global__ __launch_bounds__(256)
void transpose_pack(const float* __restrict__ src, unsigned* __restrict__ dst)
{
    __shared__ float tile[64][65];
    const int f  = blockIdx.z;
    const int n0 = blockIdx.x * 64;          // s base
    const int m0 = blockIdx.y * 64;          // v base
    const int t  = threadIdx.x;
    const int q  = t & 15;
    const int r  = t >> 4;
    const float* sp_ = src + (long)f * VS_;

#pragma unroll
    for (int i = 0; i < 4; ++i) {
        const int m = m0 + r + i * 16;
        const int n = n0 + q * 4;
        if (m < V_) {
            const float4 x = ld4(sp_ + (long)m * S_ + n);
            tile[r + i * 16][q * 4 + 0] = x.x;
            tile[r + i * 16][q * 4 + 1] = x.y;
            tile[r + i * 16][q * 4 + 2] = x.z;
            tile[r + i * 16][q * 4 + 3] = x.w;
        }
    }
    __syncthreads();

    // write: 32 s-pair rows x 16 v-quads (uint4 = 4 v x half2)
#pragma unroll
    for (int i = 0; i < 2; ++i) {
        const int idx = t + i * 256;         // 0..511
        const int vq  = idx & 15;
        const int sp  = idx >> 4;            // 0..31
        const int m   = m0 + vq * 4;
        if (m + 4 <= VP_) {
            unsigned u[4];
#pragma unroll
            for (int e = 0; e < 4; ++e)
                u[e] = packh2(tile[vq * 4 + e][2 * sp],
                              tile[vq * 4 + e][2 * sp + 1]);
            *reinterpret_cast<uint4*>(
                dst + (long)f * PLH + (long)(n0 / 2 + sp) * VP_ + m) =
                make_uint4(u[0], u[1], u[2], u[3]);
        }
    }
}

// ---------------------------------------------------------------------------
// cheb_rec: TWO s-slices per block, state packed f16x2 in LDS (verified
// 64-VGPR structure). x0 plane now emitted from the xp-init registers
// (no separate LDS re-read pass). Emits x1..x4 to chebX1 planes.
// ---------------------------------------------------------------------------
__global__ __launch_bounds__(TPB)
void cheb_rec(const unsigned* __restrict__ inTh, // [8][SP][VP] half2
              const int*   __restrict__ cols,    // [V][8]
              const float* __restrict__ vals,    // [V][8]
              ushort* __restrict__ chebX1,       // planes x1..x4
              ushort* __restrict__ x0p)          // plane x0 (or null)
{
    extern __shared__ unsigned cur[];            // VP_*LSTR dwords = 123072 B
    const int s2 = blockIdx.x * 2;               // even slice; odd = s2+1
    const int t  = threadIdx.x;

    // fill cur[v*12 + f] = inTh[f][s2/2][v]  (already half2-packed)
    {
        const int f  = t & 7;
        const int cb = t >> 3;
        const unsigned* pl = inTh + (long)f * PLH + (long)blockIdx.x * VP_;
        for (int c = cb; c < VP_ / 4; c += TPB / 8) {
            const uint4 u = *reinterpret_cast<const uint4*>(pl + c * 4);
            cur[(c * 4 + 0) * LSTR + f] = u.x;
            cur[(c * 4 + 1) * LSTR + f] = u.y;
            cur[(c * 4 + 2) * LSTR + f] = u.z;
            cur[(c * 4 + 3) * LSTR + f] = u.w;
        }
    }
    __syncthreads();

    const __half2 two2 = __half2half2(__float2half(2.0f));

    __half2 xp[NV][8];      // x_{k-2} at own vertices (starts as x0)
#pragma unroll
    for (int j = 0; j < NV; ++j) {
        const int vr = t + j * TPB;
        const int v  = (vr < V_) ? vr : 0;
        const uint4 lo = *reinterpret_cast<const uint4*>(&cur[v * LSTR]);
        const uint4 hi = *reinterpret_cast<const uint4*>(&cur[v * LSTR + 4]);
        xp[j][0] = bits2h(lo.x); xp[j][1] = bits2h(lo.y);
        xp[j][2] = bits2h(lo.z); xp[j][3] = bits2h(lo.w);
        xp[j][4] = bits2h(hi.x); xp[j][5] = bits2h(hi.y);
        xp[j][6] = bits2h(hi.z); xp[j][7] = bits2h(hi.w);

        // 5-plane mode: emit x0 from these registers (both slices)
        if (x0p && vr < V_) {
            const unsigned p0[4] = { lo.x, lo.z, hi.x, hi.z };
            const unsigned p1[4] = { lo.y, lo.w, hi.y, hi.w };
            unsigned ue[4], uo[4];
#pragma unroll
            for (int i = 0; i < 4; ++i) {
                ue[i] = __builtin_amdgcn_perm(p1[i], p0[i], 0x05040100u);
                uo[i] = __builtin_amdgcn_perm(p1[i], p0[i], 0x07060302u);
            }
            const long base = ((long)s2 * V_ + v) * 8;
            *reinterpret_cast<uint4*>(x0p + base) =
                make_uint4(ue[0], ue[1], ue[2], ue[3]);
            *reinterpret_cast<uint4*>(x0p + base + (long)V_ * 8) =
                make_uint4(uo[0], uo[1], uo[2], uo[3]);
        }
    }

#pragma unroll 1
    for (int k = 1; k < 5; ++k) {
        __half2 xk[NV][8];
#pragma unroll
        for (int j = 0; j < NV; ++j) {
            const bool valid = (t + j * TPB) < V_;
            const int v = valid ? (t + j * TPB) : 0;
            int off = v * 8;
            asm volatile("" : "+v"(off));       // block LICM of k-invariant loads
            const int4   ca = *reinterpret_cast<const int4*>(cols + off);
            const int4   cb = *reinterpret_cast<const int4*>(cols + off + 4);
            const float4 wa = ld4(vals + off);
            const float4 wb = ld4(vals + off + 4);
            const int   cc[8] = {ca.x, ca.y, ca.z, ca.w, cb.x, cb.y, cb.z, cb.w};
            const float ww[8] = {wa.x, wa.y, wa.z, wa.w, wb.x, wb.y, wb.z, wb.w};

            __half2 a[8];
#pragma unroll
            for (int e = 0; e < 8; ++e) a[e] = bits2h(0u);
#pragma unroll
            for (int n = 0; n < 8; ++n) {
                const unsigned* p = &cur[cc[n] * LSTR];
                const uint4 lo = *reinterpret_cast<const uint4*>(p);
                const uint4 hi = *reinterpret_cast<const uint4*>(p + 4);
                const __half2 w2 = __half2half2(__float2half(ww[n]));
                a[0] = __hfma2(w2, bits2h(lo.x), a[0]);
                a[1] = __hfma2(w2, bits2h(lo.y), a[1]);
                a[2] = __hfma2(w2, bits2h(lo.z), a[2]);
                a[3] = __hfma2(w2, bits2h(lo.w), a[3]);
                a[4] = __hfma2(w2, bits2h(hi.x), a[4]);
                a[5] = __hfma2(w2, bits2h(hi.y), a[5]);
                a[6] = __hfma2(w2, bits2h(hi.z), a[6]);
                a[7] = __hfma2(w2, bits2h(hi.w), a[7]);
            }
#pragma unroll
            for (int e = 0; e < 8; ++e)
                xk[j][e] = (k == 1) ? a[e]
                                    : __hfma2(two2, a[e], __hneg2(xp[j][e]));

            // emit both slices: v_perm extracts lo/hi f16 halves into dwords
            if (valid) {
                unsigned ue[4], uo[4];
#pragma unroll
                for (int i = 0; i < 4; ++i) {
                    const unsigned b0 = h2bits(xk[j][2 * i]);
                    const unsigned b1 = h2bits(xk[j][2 * i + 1]);
                    ue[i] = __builtin_amdgcn_perm(b1, b0, 0x05040100u); // even s
                    uo[i] = __builtin_amdgcn_perm(b1, b0, 0x07060302u); // odd  s
                }
                const long base = (((long)(k - 1) * S_ + s2) * V_ + v) * 8;
                *reinterpret_cast<uint4*>(chebX1 + base) =
                    make_uint4(ue[0], ue[1], ue[2], ue[3]);
                *reinterpret_cast<uint4*>(chebX1 + base + (long)V_ * 8) =
                    make_uint4(uo[0], uo[1], uo[2], uo[3]);
            }

            // stage next xprev = x_{k-1}[own] (cur stable until barrier)
            if (k < 4) {
                const uint4 lo = *reinterpret_cast<const uint4*>(&cur[v * LSTR]);
                const uint4 hi = *reinterpret_cast<const uint4*>(&cur[v * LSTR + 4]);
                xp[j][0] = bits2h(lo.x); xp[j][1] = bits2h(lo.y);
                xp[j][2] = bits2h(lo.z); xp[j][3] = bits2h(lo.w);
                xp[j][4] = bits2h(hi.x); xp[j][5] = bits2h(hi.y);
                xp[j][6] = bits2h(hi.z); xp[j][7] = bits2h(hi.w);
            }
        }
        if (k < 4) {
            __syncthreads();
#pragma unroll
            for (int j = 0; j < NV; ++j) {
                const int vr = t + j * TPB;
                if (vr < V_) {
                    *reinterpret_cast<uint4*>(&cur[vr * LSTR]) =
                        make_uint4(h2bits(xk[j][0]), h2bits(xk[j][1]),
                                   h2bits(xk[j][2]), h2bits(xk[j][3]));
                    *reinterpret_cast<uint4*>(&cur[vr * LSTR + 4]) =
                        make_uint4(h2bits(xk[j][4]), h2bits(xk[j][5]),
                                   h2bits(xk[j][6]), h2bits(xk[j][7]));
                }
            }
            __syncthreads();
        }
    }
}

// ---------------------------------------------------------------------------
// proj5: out[o][v][s] = bias[o] + sum_{k,f} W[k,f,o] * x_k[f,v,s]
// acc held as float2[8]: paired fmaf on contiguous o-pairs (SLP target
// for v_pk_fma_f32), W loaded as 8B float2 (uniform -> s_load_dwordx2).
// Same accumulation order per o -> bit-identical results.
// ---------------------------------------------------------------------------
__global__ __launch_bounds__(TPB)
void proj5(const ushort* __restrict__ cheb,      // [5][S][V][8] f16 bits
           const float* __restrict__ W,          // [5][8][16]
           const float* __restrict__ bias,       // [16]
           float* __restrict__ out)              // [FOUT][V][S]
{
    extern __shared__ float sm[];                // 16*64*17 floats = 69632 B
    const int v0 = blockIdx.x * 64;
    const int s0 = blockIdx.y * 16;
    const int t  = threadIdx.x;
    const int tv = t & 63;
    const int ts = t >> 6;
    const int vg = (v0 + tv < V_) ? (v0 + tv) : (V_ - 1);

    int4 ck[5];
#pragma unroll
    for (int k = 0; k < 5; ++k)
        ck[k] = *reinterpret_cast<const int4*>(
            cheb + (long)k * PS + ((long)(s0 + ts) * V_ + vg) * 8);

    float2 acc2[8];
#pragma unroll
    for (int p = 0; p < 8; ++p)
        acc2[p] = *reinterpret_cast<const float2*>(&bias[2 * p]);

#pragma unroll
    for (int k = 0; k < 5; ++k) {
        union { int4 q; __half u[8]; } pk;
        pk.q = ck[k];
        float xf[8];
#pragma unroll
        for (int f = 0; f < 8; ++f)
            xf[f] = __half2float(pk.u[f]);
#pragma unroll
        for (int f = 0; f < 8; ++f) {
            const float* wr = &W[(k * 8 + f) * 16];
#pragma unroll
            for (int p = 0; p < 8; ++p) {
                const float2 w2 = *reinterpret_cast<const float2*>(&wr[2 * p]);
                acc2[p].x = fmaf(w2.x, xf[f], acc2[p].x);
                acc2[p].y = fmaf(w2.y, xf[f], acc2[p].y);
            }
        }
    }

    // one-shot staging: all 16 o planes, then vectorized stores
#pragma unroll
    for (int p = 0; p < 8; ++p) {
        sm[(2 * p)     * 1088 + tv * 17 + ts] = acc2[p].x;
        sm[(2 * p + 1) * 1088 + tv * 17 + ts] = acc2[p].y;
    }
    __syncthreads();
#pragma unroll
    for (int p = 0; p < 4; ++p) {
        const int idx = t + p * TPB;             // 0..4095
        const int sq  = idx & 3;
        const int v   = (idx >> 2) & 63;
        const int o   = idx >> 8;                // 0..15
        if (v0 + v < V_) {
            const float* r = &sm[o * 1088 + v * 17 + sq * 4];
            st4(out + (long)o * VS_ + (long)(v0 + v) * S_ + s0 + sq * 4,
                make_float4(r[0], r[1], r[2], r[3]));
        }
    }
}

// ---------------------------------------------------------------------------
// proj4: fallback when ws_size < 5 planes (in + 4-plane cheb).
// ---------------------------------------------------------------------------
__global__ __launch_bounds__(TPB)
void proj4(const float* __restrict__ in,         // [FIN][V][S]
           const ushort* __restrict__ cheb,      // [4][S][V][8] f16 bits
           const float* __restrict__ W,
           const float* __restrict__ bias,
           float* __restrict__ out)
{
    extern __shared__ float sm[];                // 16*64*17 floats
    const int v0 = blockIdx.x * 64;
    const int s0 = blockIdx.y * 16;
    const int t  = threadIdx.x;
    const int tv = t & 63;
    const int ts = t >> 6;
    const int vg = (v0 + tv < V_) ? (v0 + tv) : (V_ - 1);

    int4 ck[4];
#pragma unroll
    for (int k = 0; k < 4; ++k)
        ck[k] = *reinterpret_cast<const int4*>(
            cheb + (long)k * PS + ((long)(s0 + ts) * V_ + vg) * 8);

#pragma unroll
    for (int p = 0; p < 2; ++p) {
        const int idx = t + p * TPB;
        const int sq  = idx & 3;
        const int v   = (idx >> 2) & 63;
        const int f   = idx >> 8;
        const int vvg = (v0 + v < V_) ? (v0 + v) : (V_ - 1);
        const float4 x = ld4(in + (long)f * VS_ + (long)vvg * S_ + s0 + sq * 4);
        float* d = &sm[f * 1088 + v * 17 + sq * 4];
        d[0] = x.x; d[1] = x.y; d[2] = x.z; d[3] = x.w;
    }
    __syncthreads();

    float acc[16];
#pragma unroll
    for (int o = 0; o < 16; ++o) acc[o] = bias[o];

#pragma unroll
    for (int f = 0; f < FIN_; ++f) {
        const float xv = sm[f * 1088 + tv * 17 + ts];
#pragma unroll
        for (int o = 0; o < 16; ++o)
            acc[o] = fmaf(W[f * 16 + o], xv, acc[o]);
    }
#pragma unroll
    for (int k = 1; k < 5; ++k) {
        union { int4 q; __half u[8]; } pk;
        pk.q = ck[k - 1];
        float xf[8];
#pragma unroll
        for (int f = 0; f < 8; ++f)
            xf[f] = __half2float(pk.u[f]);
#pragma unroll
        for (int f = 0; f < 8; ++f) {
#pragma unroll
            for (int o = 0; o < 16; ++o)
                acc[o] = fmaf(W[(k * 8 + f) * 16 + o], xf[f], acc[o]);
        }
    }

    __syncthreads();
#pragma unroll
    for (int o = 0; o < 16; ++o)
        sm[o * 1088 + tv * 17 + ts] = acc[o];
    __syncthreads();
#pragma unroll
    for (int p = 0; p < 4; ++p) {
        const int idx = t + p * TPB;
        const int sq  = idx & 3;
        const int v   = (idx >> 2) & 63;
        const int o   = idx >> 8;
        if (v0 + v < V_) {
            const float* r = &sm[o * 1088 + v * 17 + sq * 4];
            st4(out + (long)o * VS_ + (long)(v0 + v) * S_ + s0 + sq * 4,
                make_float4(r[0], r[1], r[2], r[3]));
        }
    }
}

extern "C" void kernel_launch(void* const* d_in, const int* in_sizes, int n_in,
                              void* d_out, int out_size, void* d_ws, size_t ws_size,
                              hipStream_t stream) {
    const float* in   = (const float*)d_in[0];
    // d_in[1] = lap_rows == repeat(arange(V), DEG) by construction -> implicit
    const int*   cols = (const int*)d_in[2];
    const float* vals = (const float*)d_in[3];
    const float* W    = (const float*)d_in[4];
    const float* bias = (const float*)d_in[5];
    float* out = (float*)d_out;

    // inTh f16 (21 MB) borrows d_out (fully consumed by cheb_rec before
    // proj overwrites d_out). cheb planes live in d_ws:
    //   5-plane mode (x0..x4, 105 MB) if workspace allows, else 4-plane.
    unsigned* inTh = (unsigned*)d_out;
    const bool five = ws_size >= (size_t)(5 * PS * 2);
    ushort* wsu    = (ushort*)d_ws;
    ushort* x0p    = five ? wsu : nullptr;
    ushort* chebX1 = five ? wsu + PS : wsu;

    (void)hipFuncSetAttribute((const void*)cheb_rec,
                              hipFuncAttributeMaxDynamicSharedMemorySize,
                              VP_ * LSTR * (int)sizeof(unsigned));
    (void)hipFuncSetAttribute((const void*)proj5,
                              hipFuncAttributeMaxDynamicSharedMemorySize,
                              16 * 64 * 17 * (int)sizeof(float));
    (void)hipFuncSetAttribute((const void*)proj4,
                              hipFuncAttributeMaxDynamicSharedMemorySize,
                              16 * 64 * 17 * (int)sizeof(float));

    // T1: in[f][v][s] f32 -> inTh[f][s/2][v] half2
    transpose_pack<<<dim3(8, 41, 8), 256, 0, stream>>>(in, inTh);

    // Recursion: 2 s-slices per block, emit x1..x4 (+x0 in 5-plane mode)
    cheb_rec<<<dim3(SP_), TPB, VP_ * LSTR * (int)sizeof(unsigned), stream>>>(
        inTh, cols, vals, chebX1, x0p);

    // Projection + output transpose
    if (five)
        proj5<<<dim3(41, 32), TPB, 16 * 64 * 17 * (int)sizeof(float), stream>>>(
            wsu, W, bias, out);
    else
        proj4<<<dim3(41, 32), TPB, 16 * 64 * 17 * (int)sizeof(float), stream>>>(
            in, chebX1, W, bias, out);
}